// Round 6
// baseline (215.076 us; speedup 1.0000x reference)
//
#include <hip/hip_runtime.h>

#define D_DIM 640
#define M_DIM 1024
#define B_DIM 32
#define OUT_ROW 205120  // 640*641/2

typedef __bf16 bf16x8 __attribute__((ext_vector_type(8)));
typedef float f32x4 __attribute__((ext_vector_type(4)));

__device__ __forceinline__ unsigned short f2bf(float f) {
    union { float f; unsigned int u; } c; c.f = f;
    unsigned int u = c.u;
    unsigned int r = (u + 0x7fffu + ((u >> 16) & 1u)) >> 16;
    return (unsigned short)r;
}

__device__ __forceinline__ float bf2f(unsigned short h) {
    union { unsigned int u; float f; } c; c.u = ((unsigned int)h) << 16;
    return c.f;
}

__device__ __forceinline__ void gload_lds16(const unsigned short* g, unsigned short* l) {
    __builtin_amdgcn_global_load_lds(
        (const __attribute__((address_space(1))) unsigned int*)g,
        (__attribute__((address_space(3))) unsigned int*)l,
        16, 0, 0);
}

__device__ __forceinline__ float block_reduce_256(float s) {
    #pragma unroll
    for (int off = 32; off > 0; off >>= 1) s += __shfl_down(s, off, 64);
    __shared__ float red[4];
    if ((threadIdx.x & 63) == 0) red[threadIdx.x >> 6] = s;
    __syncthreads();
    return red[0] + red[1] + red[2] + red[3];
}

__device__ __forceinline__ float block_reduce_1024(float s) {
    #pragma unroll
    for (int off = 32; off > 0; off >>= 1) s += __shfl_down(s, off, 64);
    __shared__ float red[16];
    if ((threadIdx.x & 63) == 0) red[threadIdx.x >> 6] = s;
    __syncthreads();
    float t = 0.f;
    #pragma unroll
    for (int i = 0; i < 16; i++) t += red[i];
    return t;
}

// Kernel 1: fp32 -> bf16 cast + per-row sum of squares; zeroes accumulators.
__global__ void cast_diag_kernel(const float* __restrict__ x,
                                 unsigned short* __restrict__ xb,
                                 float* __restrict__ diag,
                                 float* __restrict__ rowsum,
                                 float* __restrict__ tot) {
    const size_t row = blockIdx.x;
    const int t = threadIdx.x;
    const float4 v = ((const float4*)(x + row * M_DIM))[t];
    float s = v.x * v.x + v.y * v.y + v.z * v.z + v.w * v.w;
    ushort4 o;
    o.x = f2bf(v.x); o.y = f2bf(v.y); o.z = f2bf(v.z); o.w = f2bf(v.w);
    ((ushort4*)(xb + row * M_DIM))[t] = o;
    float ssum = block_reduce_256(s);
    if (t == 0) { diag[row] = ssum; rowsum[row] = 0.f; }
    if (t == 1 && row < B_DIM) tot[row] = 0.f;
}

// Kernel 2: symmetric batched G = X X^T with 256x256 MACRO-TILES.
// r0-r5 post-mortem: gemm time tracks staged-read traffic (~6-8 TB/s
// L2/L3 delivery wall; per-XCD working set 5 MB > 4 MB L2), NOT the
// schedule — r5's zero-barrier variant proved barriers weren't the cost.
// So: halve traffic via tile size. s=128 -> 245 MB (r0); s=256 -> ~160 MB.
// 6 macro-tiles/batch over bands {256,256,128} (upper-tri), 192 blocks x
// 1024 threads (16 waves, 4x4 grid, 64x64 per wave = r5-proven acc[4][4]
// math), on the PROVEN r0/r1 4-phase/depth-3/one-barrier skeleton
// (4 x 32 KB = 128 KB LDS, vmcnt ladder 4/2/0, 2 gloads/issue).
// Ragged edges: staging rows clamped in-range (no OOB/NaN); epilogue is
// ELEMENT-MASKED (up = grow<=gcol, mirror if strict) — every strictly-
// lower matrix element is the mirror of exactly one computed strict-upper
// element, so rowsum/tot accounting is uniform with no diagTile special
// case. Dead waves (fully-lower or out-of-band) skip ds_read/MFMA/epilogue
// but keep wait+barrier+issue (wave-uniform branch).
__global__ __launch_bounds__(1024)
void gemm_dcov_kernel(const unsigned short* __restrict__ xb,
                      const float* __restrict__ diag,
                      unsigned short* __restrict__ dcov,
                      float* __restrict__ rowsum,
                      float* __restrict__ tot) {
    // 4 phases x (A 256x32 = 8192 shorts + B 256x32 = 8192 shorts) = 128 KB
    __shared__ __align__(16) unsigned short smem[65536];

    const int id = blockIdx.x;            // 0..191
    const int xcd = id & 7;
    const int k6 = id >> 3;               // 0..23
    const int bt = xcd + 8 * (k6 / 6);    // 4 batches per XCD, clustered
    const int mc = k6 % 6;                // macro index
    const int R = (mc < 3) ? 0 : ((mc < 5) ? 1 : 2);
    const int C = (mc < 3) ? mc : ((mc < 5) ? (mc - 2) : 2);
    const int h = (R == 2) ? 128 : 256;   // valid rows in this macro
    const int wd = (C == 2) ? 128 : 256;  // valid cols in this macro

    const int tid = threadIdx.x;
    const int w = tid >> 6, l = tid & 63;
    const int wy = w >> 2, wx = w & 3;    // 4x4 wave grid, 64x64 per wave
    const int lm = l & 15, quad = l >> 4;
    const bool alive = (wy * 64 < h) && (wx * 64 < wd) && (R != C || wy <= wx);

    const unsigned short* gA = xb + ((size_t)bt * D_DIM + R * 256) * M_DIM;
    const unsigned short* gB = xb + ((size_t)bt * D_DIM + C * 256) * M_DIM;

    // staging: gload_lds writes LDS at (uniform base + lane*16B); pick the
    // per-lane GLOBAL source chunk so LDS lands XOR-swizzled.
    // Invariant: LDS[row][slot c] holds global chunk c ^ ((row>>1)&3).
    const int r0 = tid >> 2;              // LDS row 0..255
    const int cl = (((tid & 3) ^ ((tid >> 3) & 3)) << 3);
    const int ra = (r0 < h) ? r0 : (r0 & 63);   // clamp ragged rows in-range
    const int rb = (r0 < wd) ? r0 : (r0 & 63);
    const size_t aoffA = (size_t)ra * M_DIM + cl;
    const size_t aoffB = (size_t)rb * M_DIM + cl;
    const int ldst = tid * 8;             // shorts; 1024*8 = 8192 = 16 KB

    auto issue = [&](int k, int ph) {
        unsigned short* sA = smem + ph * 16384;
        unsigned short* sB = sA + 8192;
        const int koff = k * 32;
        gload_lds16(gA + aoffA + koff, sA + ldst);
        gload_lds16(gB + aoffB + koff, sB + ldst);
    };

    f32x4 acc[4][4];
    const f32x4 zero = {0.f, 0.f, 0.f, 0.f};
    #pragma unroll
    for (int i = 0; i < 4; i++)
        #pragma unroll
        for (int j = 0; j < 4; j++) acc[i][j] = zero;

    const int sw = ((quad ^ ((lm >> 1) & 3)) << 3);  // swizzled read slot

    issue(0, 0); issue(1, 1); issue(2, 2);  // 6 loads in flight (depth-3)

    for (int k = 0; k < 32; ++k) {
        // wait only for phase k's 2 loads; keep 4 more in flight.
        if (k < 30)       asm volatile("s_waitcnt vmcnt(4)" ::: "memory");
        else if (k == 30) asm volatile("s_waitcnt vmcnt(2)" ::: "memory");
        else              asm volatile("s_waitcnt vmcnt(0)" ::: "memory");
        asm volatile("s_barrier" ::: "memory");
        // prefetch k+3 into phase (k+3)&3 = buffer last read at iter k-1,
        // which the top-of-loop barrier already protects (proven r0/r1 form).
        if (k + 3 < 32) issue(k + 3, (k + 3) & 3);

        if (alive) {
            const unsigned short* sA = smem + (k & 3) * 16384;
            const unsigned short* sB = sA + 8192;
            bf16x8 af[4], bfr[4];
            #pragma unroll
            for (int mi = 0; mi < 4; mi++)
                af[mi] = *(const bf16x8*)&sA[(wy * 64 + mi * 16 + lm) * 32 + sw];
            #pragma unroll
            for (int ni = 0; ni < 4; ni++)
                bfr[ni] = *(const bf16x8*)&sB[(wx * 64 + ni * 16 + lm) * 32 + sw];

            #pragma unroll
            for (int mi = 0; mi < 4; mi++)
                #pragma unroll
                for (int ni = 0; ni < 4; ni++)
                    acc[mi][ni] = __builtin_amdgcn_mfma_f32_16x16x32_bf16(
                        af[mi], bfr[ni], acc[mi][ni], 0, 0, 0);
        }
    }

    // stage diag slices in LDS (all gloads drained by k=31's vmcnt(0))
    float* sd = (float*)smem;
    const float* dg = diag + (size_t)bt * D_DIM;
    if (tid < 256) {
        const int rr = R * 256 + tid;
        sd[tid] = dg[rr < D_DIM ? rr : (D_DIM - 1)];
    } else if (tid < 512) {
        const int cc = C * 256 + (tid - 256);
        sd[tid] = dg[cc < D_DIM ? cc : (D_DIM - 1)];
    }
    __syncthreads();

    const float temp = 7.62939453125e-07f;  // 1/(2*640*1024)
    unsigned short* dbase = dcov + (size_t)bt * D_DIM * D_DIM;
    float* rs = rowsum + (size_t)bt * D_DIM;
    float ts = 0.f;

    if (alive) {
        float cp[4] = {0.f, 0.f, 0.f, 0.f};
        #pragma unroll
        for (int mi = 0; mi < 4; mi++) {
            #pragma unroll
            for (int r = 0; r < 4; r++) {
                const int lrow = wy * 64 + mi * 16 + quad * 4 + r;
                const int grow = R * 256 + lrow;
                const float di = sd[lrow];
                float rp = 0.f;
                #pragma unroll
                for (int ni = 0; ni < 4; ni++) {
                    const int lcol = wx * 64 + ni * 16 + lm;
                    const int gcol = C * 256 + lcol;
                    const float dj = sd[256 + lcol];
                    const float g = acc[mi][ni][r];
                    const float v = sqrtf(fmaf(temp, fmaxf(di + dj - 2.f * g, 0.f), 1e-5f));
                    const bool up = (grow <= gcol);
                    const bool strict = (grow < gcol);
                    if (up) dbase[(size_t)grow * D_DIM + gcol] = f2bf(v);
                    const float vp = up ? v : 0.f;
                    const float vm = strict ? v : 0.f;
                    rp += vp;
                    cp[ni] += vm;     // mirror: lower element (gcol,grow)
                    ts += vp + vm;
                }
                rp += __shfl_down(rp, 8, 16);
                rp += __shfl_down(rp, 4, 16);
                rp += __shfl_down(rp, 2, 16);
                rp += __shfl_down(rp, 1, 16);
                if (lm == 0) atomicAdd(&rs[grow], rp);
            }
        }
        // mirrored lower elements: their row sums == our column sums
        #pragma unroll
        for (int ni = 0; ni < 4; ni++) {
            float c = cp[ni];
            c += __shfl_down(c, 32);
            c += __shfl_down(c, 16);
            if (l < 16) atomicAdd(&rs[C * 256 + wx * 64 + ni * 16 + lm], c);
        }
    }
    float bs = block_reduce_1024(ts);
    if (tid == 0) atomicAdd(&tot[bt], bs);
}

// Kernel 3: double centering + triu gather (bf16 dcov read, fp32 out).
// Balanced: block q handles rows q and 639-q (lengths 640-q and q+1, sum 641).
__global__ void output_kernel(const unsigned short* __restrict__ dcov,
                              const float* __restrict__ rowsum,
                              const float* __restrict__ tot,
                              float* __restrict__ out) {
    const int b = blockIdx.x / 320;
    const int q = blockIdx.x - b * 320;
    const float inv_d = 1.f / (float)D_DIM;
    const float tm = tot[b] * (inv_d * inv_d);
    const float* rs = rowsum + (size_t)b * D_DIM;

    #pragma unroll
    for (int half = 0; half < 2; half++) {
        const int i = half ? (D_DIM - 1 - q) : q;
        const float rmi = rs[i] * inv_d;
        const unsigned short* drow = dcov + ((size_t)b * D_DIM + i) * D_DIM;
        float* orow = out + (size_t)b * OUT_ROW + (size_t)i * D_DIM - (size_t)i * (i - 1) / 2;
        for (int j = i + threadIdx.x; j < D_DIM; j += 256)
            orow[j - i] = bf2f(drow[j]) - rmi - rs[j] * inv_d + tm;
    }
}

extern "C" void kernel_launch(void* const* d_in, const int* in_sizes, int n_in,
                              void* d_out, int out_size, void* d_ws, size_t ws_size,
                              hipStream_t stream) {
    const float* x = (const float*)d_in[0];
    float* out = (float*)d_out;

    char* ws = (char*)d_ws;
    unsigned short* xb = (unsigned short*)ws;                 // 41,943,040 B
    size_t off = 41943040;
    float* diag = (float*)(ws + off);           off += 81920;
    unsigned short* dcov = (unsigned short*)(ws + off); off += 26214400;  // bf16
    float* rowsum = (float*)(ws + off);         off += 81920;
    float* tot = (float*)(ws + off);            off += 256;

    cast_diag_kernel<<<dim3(B_DIM * D_DIM), 256, 0, stream>>>(x, xb, diag, rowsum, tot);
    gemm_dcov_kernel<<<dim3(192), 1024, 0, stream>>>(xb, diag, dcov, rowsum, tot);
    output_kernel<<<dim3(B_DIM * 320), 256, 0, stream>>>(dcov, rowsum, tot, out);
}

// Round 7
// 173.038 us; speedup vs baseline: 1.2429x; 1.2429x over previous
//
#include <hip/hip_runtime.h>

#define D_DIM 640
#define M_DIM 1024
#define B_DIM 32
#define OUT_ROW 205120  // 640*641/2

typedef __bf16 bf16x8 __attribute__((ext_vector_type(8)));
typedef float f32x4 __attribute__((ext_vector_type(4)));

__device__ __forceinline__ unsigned short f2bf(float f) {
    union { float f; unsigned int u; } c; c.f = f;
    unsigned int u = c.u;
    unsigned int r = (u + 0x7fffu + ((u >> 16) & 1u)) >> 16;
    return (unsigned short)r;
}

__device__ __forceinline__ float bf2f(unsigned short h) {
    union { unsigned int u; float f; } c; c.u = ((unsigned int)h) << 16;
    return c.f;
}

__device__ __forceinline__ void gload_lds16(const unsigned short* g, unsigned short* l) {
    __builtin_amdgcn_global_load_lds(
        (const __attribute__((address_space(1))) unsigned int*)g,
        (__attribute__((address_space(3))) unsigned int*)l,
        16, 0, 0);
}

__device__ __forceinline__ float block_reduce_256(float s) {
    #pragma unroll
    for (int off = 32; off > 0; off >>= 1) s += __shfl_down(s, off, 64);
    __shared__ float red[4];
    if ((threadIdx.x & 63) == 0) red[threadIdx.x >> 6] = s;
    __syncthreads();
    return red[0] + red[1] + red[2] + red[3];
}

// Kernel 1: fp32 -> bf16 cast + per-row sum of squares; zeroes accumulators.
__global__ void cast_diag_kernel(const float* __restrict__ x,
                                 unsigned short* __restrict__ xb,
                                 float* __restrict__ diag,
                                 float* __restrict__ rowsum,
                                 float* __restrict__ tot) {
    const size_t row = blockIdx.x;
    const int t = threadIdx.x;
    const float4 v = ((const float4*)(x + row * M_DIM))[t];
    float s = v.x * v.x + v.y * v.y + v.z * v.z + v.w * v.w;
    ushort4 o;
    o.x = f2bf(v.x); o.y = f2bf(v.y); o.z = f2bf(v.z); o.w = f2bf(v.w);
    ((ushort4*)(xb + row * M_DIM))[t] = o;
    float ssum = block_reduce_256(s);
    if (t == 0) { diag[row] = ssum; rowsum[row] = 0.f; }
    if (t == 1 && row < B_DIM) tot[row] = 0.f;
}

// Kernel 2: symmetric batched G = X X^T, upper-tri 128-blocks split into
// 128x64 tiles (it<=jt, jh in {0,1}), fused dcov epilogue + rowsum/tot.
// r0-r6 post-mortem: gemm time tracks RESIDENT INDEPENDENT BLOCKS PER CU
// (with zero grid starvation), not barrier count (r5 zero-barrier: worse),
// not traffic (r6 lowest-traffic: worst — 192 blocks left 25% of CUs idle
// at 1 block/CU). No round had both slots>2 AND demand>=slots.
// THIS ROUND: r4's proven grid (960 blocks x 256 thr, 128x64 tiles) on the
// minimal CLASSIC 2-phase / 2-barrier pipeline (m97-proven, race-free by
// construction): 2 x 12 KB = 24 KB LDS -> 6 blocks/CU capacity vs 3.75
// demand = full co-residency, ~15 waves/CU in ~4 independent domains.
// Safety: issue(k+1) targets buffer (k+1)&1, whose iter-(k-1) reads all
// completed before the iter-(k-1) TRAILING barrier; every wave is past it.
// vmcnt(3) at iter k waits exactly phase k's 3 loads (3 newer in flight).
__global__ __launch_bounds__(256, 6)
void gemm_dcov_kernel(const unsigned short* __restrict__ xb,
                      const float* __restrict__ diag,
                      unsigned short* __restrict__ dcov,
                      float* __restrict__ rowsum,
                      float* __restrict__ tot) {
    // 2 phases x (A 128x32 = 4096 shorts + B 64x32 = 2048 shorts) = 24 KB
    __shared__ __align__(16) unsigned short smem[12288];

    const int id = blockIdx.x;
    const int bt = (id & 7) * 4 + ((id >> 3) & 3);  // batch; same-batch tiles share an XCD
    const int rest = id >> 5;                        // 0..29
    const int jh = rest & 1;                         // column half of the 128-block
    int p2 = rest >> 1;                              // 0..14 tile-pair index
    int it = 0, off = p2;
    while (off >= 5 - it) { off -= 5 - it; ++it; }
    const int jt = it + off;
    const bool diagTile = (it == jt);

    const int tid = threadIdx.x;
    const int w = tid >> 6, l = tid & 63;
    const int wy = w >> 1, wx = w & 1;               // 2 row-bands x 2 col-bands
    const int lm = l & 15, quad = l >> 4;

    const unsigned short* gA = xb + ((size_t)bt * D_DIM + it * 128) * M_DIM;
    const unsigned short* gB = xb + ((size_t)bt * D_DIM + jt * 128 + jh * 64) * M_DIM;

    // staging: lane writes LDS at tid*16B (fixed by global_load_lds); pick the
    // global source chunk so LDS gets XOR-swizzled (bank-conflict-free reads).
    // Invariant: LDS[row][slot c] holds global chunk c ^ ((row>>1)&3).
    const int r0 = tid >> 2;                         // 0..63
    const int cl = (((tid & 3) ^ ((tid >> 3) & 3)) << 3);
    const size_t aoff = (size_t)r0 * M_DIM + cl;
    const int ldst = tid * 8;                        // shorts; 256*8 = 2048 = 4 KB

    auto issue = [&](int k, int ph) {
        unsigned short* sA = smem + ph * 6144;
        unsigned short* sB = sA + 4096;
        const int koff = k * 32;
        gload_lds16(gA + aoff + koff, sA + ldst);                             // A rows 0..63
        gload_lds16(gA + aoff + (size_t)64 * M_DIM + koff, sA + ldst + 2048); // A rows 64..127
        gload_lds16(gB + aoff + koff, sB + ldst);                             // B rows 0..63
    };

    f32x4 acc[4][2];
    const f32x4 zero = {0.f, 0.f, 0.f, 0.f};
    #pragma unroll
    for (int i = 0; i < 4; i++)
        #pragma unroll
        for (int j = 0; j < 2; j++) acc[i][j] = zero;

    const int sw = ((quad ^ ((lm >> 1) & 3)) << 3);  // swizzled chunk offset

    issue(0, 0);  // prologue: phase 0 in flight

    for (int k = 0; k < 32; ++k) {
        // prefetch k+1 into the other buffer (its iter k-1 readers all
        // passed the trailing barrier), then wait phase k's 3 loads only.
        if (k + 1 < 32) {
            issue(k + 1, (k + 1) & 1);
            asm volatile("s_waitcnt vmcnt(3)" ::: "memory");
        } else {
            asm volatile("s_waitcnt vmcnt(0)" ::: "memory");
        }
        asm volatile("s_barrier" ::: "memory");       // phase k visible to all

        const unsigned short* sA = smem + (k & 1) * 6144;
        const unsigned short* sB = sA + 4096;
        bf16x8 af[4], bfr[2];
        #pragma unroll
        for (int mi = 0; mi < 4; mi++)
            af[mi] = *(const bf16x8*)&sA[(wy * 64 + mi * 16 + lm) * 32 + sw];
        #pragma unroll
        for (int ni = 0; ni < 2; ni++)
            bfr[ni] = *(const bf16x8*)&sB[(wx * 32 + ni * 16 + lm) * 32 + sw];

        #pragma unroll
        for (int mi = 0; mi < 4; mi++)
            #pragma unroll
            for (int ni = 0; ni < 2; ni++)
                acc[mi][ni] = __builtin_amdgcn_mfma_f32_16x16x32_bf16(
                    af[mi], bfr[ni], acc[mi][ni], 0, 0, 0);

        asm volatile("s_barrier" ::: "memory");       // reads done before overwrite
    }

    // stage diag slices in LDS (past the final trailing barrier: all phase
    // reads complete, vmcnt(0) drained all staging writes)
    float* sd = (float*)smem;
    if (tid < 128)      sd[tid] = diag[(size_t)bt * D_DIM + it * 128 + tid];
    else if (tid < 192) sd[tid] = diag[(size_t)bt * D_DIM + jt * 128 + jh * 64 + (tid - 128)];
    __syncthreads();

    const float temp = 7.62939453125e-07f;  // 1/(2*640*1024)
    unsigned short* dbase = dcov + (size_t)bt * D_DIM * D_DIM;
    float* rs = rowsum + (size_t)bt * D_DIM;
    float ts = 0.f;
    float cp[2] = {0.f, 0.f};

    #pragma unroll
    for (int mi = 0; mi < 4; mi++) {
        #pragma unroll
        for (int r = 0; r < 4; r++) {
            const int lrow = wy * 64 + mi * 16 + quad * 4 + r;
            const int grow = it * 128 + lrow;
            const float di = sd[lrow];
            float rp = 0.f;
            #pragma unroll
            for (int ni = 0; ni < 2; ni++) {
                const int lcol = wx * 32 + ni * 16 + lm;
                const int gcol = jt * 128 + jh * 64 + lcol;
                const float dj = sd[128 + lcol];
                const float g = acc[mi][ni][r];
                const float v = sqrtf(fmaf(temp, fmaxf(di + dj - 2.f * g, 0.f), 1e-5f));
                dbase[(size_t)grow * D_DIM + gcol] = f2bf(v);
                rp += v;
                cp[ni] += v;
            }
            ts += rp;
            rp += __shfl_down(rp, 8, 16);
            rp += __shfl_down(rp, 4, 16);
            rp += __shfl_down(rp, 2, 16);
            rp += __shfl_down(rp, 1, 16);
            if (lm == 0) atomicAdd(&rs[grow], rp);
        }
    }
    if (!diagTile) {
        // mirrored lower tile (jt,it): its row sums == our column sums
        #pragma unroll
        for (int ni = 0; ni < 2; ni++) {
            float c = cp[ni];
            c += __shfl_down(c, 32);
            c += __shfl_down(c, 16);
            if (l < 16) atomicAdd(&rs[jt * 128 + jh * 64 + wx * 32 + ni * 16 + lm], c);
        }
    }
    float bs = block_reduce_256(ts);
    if (tid == 0) atomicAdd(&tot[bt], diagTile ? bs : 2.f * bs);
}

// Kernel 3: double centering + triu gather (bf16 dcov read, fp32 out).
// Balanced: block q handles rows q and 639-q (lengths 640-q and q+1, sum 641).
__global__ void output_kernel(const unsigned short* __restrict__ dcov,
                              const float* __restrict__ rowsum,
                              const float* __restrict__ tot,
                              float* __restrict__ out) {
    const int b = blockIdx.x / 320;
    const int q = blockIdx.x - b * 320;
    const float inv_d = 1.f / (float)D_DIM;
    const float tm = tot[b] * (inv_d * inv_d);
    const float* rs = rowsum + (size_t)b * D_DIM;

    #pragma unroll
    for (int half = 0; half < 2; half++) {
        const int i = half ? (D_DIM - 1 - q) : q;
        const float rmi = rs[i] * inv_d;
        const unsigned short* drow = dcov + ((size_t)b * D_DIM + i) * D_DIM;
        float* orow = out + (size_t)b * OUT_ROW + (size_t)i * D_DIM - (size_t)i * (i - 1) / 2;
        for (int j = i + threadIdx.x; j < D_DIM; j += 256)
            orow[j - i] = bf2f(drow[j]) - rmi - rs[j] * inv_d + tm;
    }
}

extern "C" void kernel_launch(void* const* d_in, const int* in_sizes, int n_in,
                              void* d_out, int out_size, void* d_ws, size_t ws_size,
                              hipStream_t stream) {
    const float* x = (const float*)d_in[0];
    float* out = (float*)d_out;

    char* ws = (char*)d_ws;
    unsigned short* xb = (unsigned short*)ws;                 // 41,943,040 B
    size_t off = 41943040;
    float* diag = (float*)(ws + off);           off += 81920;
    unsigned short* dcov = (unsigned short*)(ws + off); off += 26214400;  // bf16
    float* rowsum = (float*)(ws + off);         off += 81920;
    float* tot = (float*)(ws + off);            off += 256;

    cast_diag_kernel<<<dim3(B_DIM * D_DIM), 256, 0, stream>>>(x, xb, diag, rowsum, tot);
    gemm_dcov_kernel<<<dim3(960), 256, 0, stream>>>(xb, diag, dcov, rowsum, tot);
    output_kernel<<<dim3(B_DIM * 320), 256, 0, stream>>>(dcov, rowsum, tot, out);
}